// Round 7
// baseline (583.935 us; speedup 1.0000x reference)
//
#include <hip/hip_runtime.h>
#include <math.h>

#define NG 128
#define NIN 512
#define OFF1 4194304   // 8192*512
#define OFF2 8388608   // 2*8192*512
#define OFF3 9437184   // OFF2 + 8192*128
#define NBLK 1024      // must be <= co-resident capacity (4 blocks/CU * 256 CU)

#define INV_SQRT_2PI 0.3989422804014327f
#define INV_SQRT2    0.7071067811865476f

typedef float f32x4 __attribute__((ext_vector_type(4)));

// fast tanh: 1 - 2/(e^{2x}+1). v_exp_f32 + v_rcp_f32, ~2ulp.
__device__ __forceinline__ float ftanh(float x){
    float e = __expf(2.0f*x);
    float r = __builtin_amdgcn_rcpf(e + 1.0f);
    return 1.0f - 2.0f*r;
}
__device__ __forceinline__ float frcp(float x){ return __builtin_amdgcn_rcpf(x); }

__device__ __forceinline__ float gelu_f(float x){
    return 0.5f*x*(1.0f + erff(x*INV_SQRT2));
}
__device__ __forceinline__ float gelu_df(float x){
    return 0.5f*(1.0f + erff(x*INV_SQRT2)) + x*INV_SQRT_2PI*__expf(-0.5f*x*x);
}

// Kernel 1: tv(t), dtv/dt, truncnorm consts; ALSO zeroes dsum + barrier counter
// (d_ws is re-poisoned to 0xAA before every timed call -> must re-zero here).
__global__ void k_pre(const float* __restrict__ ts,
                      const float* __restrict__ mup, const float* __restrict__ sigp,
                      const float* __restrict__ Wt,  const float* __restrict__ bt,
                      const float* __restrict__ Wt2, const float* __restrict__ bt2,
                      float* __restrict__ tv_ws, float* __restrict__ dtv_ws,
                      float* __restrict__ consts, float* __restrict__ dsum,
                      int* __restrict__ counter){
    int g = threadIdx.x;
    if (g < NG) dsum[g] = 0.0f;
    if (g == 0){
        *counter = 0;
        float mu = mup[0], sigma = sigp[0];
        float sig2  = sigma*sigma + 1e-5f;
        float phi_b = 0.5f*(1.0f+erff((10.0f-mu)/sigma*INV_SQRT2));
        float phi_a = 0.5f*(1.0f+erff((-10.0f-mu)/sigma*INV_SQRT2));
        consts[0] = sig2;
        consts[1] = -1.0f/sig2;                                    // dlp
        consts[2] = 1.0f/(sigma*sigma*sigma*sigma + 1e-5f);        // inv_s4
        consts[3] = 1.0f/(phi_b-phi_a);                            // invZ
        consts[4] = mu;
        consts[5] = 1.0f/sigma;
        consts[6] = sigma;
    }
    if (g >= NG) return;
    float t  = ts[0];
    const float f1 = 0.01f;                     // freqs = [1, 0.01] exactly
    float s0, c0, s1, c1;
    __sincosf(t, &s0, &c0);
    __sincosf(t*f1, &s1, &c1);
    float temb[4]  = { s0, s1, c0, c1 };
    float dtemb[4] = { c0, f1*c1, -s0, -f1*s1 };
    float tg[4], dg[4];
    #pragma unroll
    for (int i=0;i<4;i++){
        float a = bt[g*4+i], d = 0.0f;
        #pragma unroll
        for (int j=0;j<4;j++){
            float w = Wt[g*16+i*4+j];
            a += w*temb[j]; d += w*dtemb[j];
        }
        tg[i] = gelu_f(a);
        dg[i] = gelu_df(a)*d;
    }
    #pragma unroll
    for (int j=0;j<4;j++){
        float a = bt2[g*4+j], d = 0.0f;
        #pragma unroll
        for (int i=0;i<4;i++){
            float w = Wt2[g*16+j*4+i];
            a += w*tg[i]; d += w*dg[i];
        }
        tv_ws[g*4+j]  = a;
        dtv_ws[g*4+j] = d;
    }
}

// Single-pass persistent kernel with manual grid barrier.
// 1024 blocks x 256 threads; launch_bounds(256,4) caps VGPR at 128 so all
// 1024 blocks are co-resident (4/CU) -> the spin barrier cannot deadlock.
// Thread = (g = tid&127, rh = tid>>7) x 4 row-iterations = 8 rows/block.
// pde (minus dSdt broadcast) parks in 16 registers across the barrier.
__global__ __launch_bounds__(256, 4) void k_all(
    const float* __restrict__ z,
    const float* __restrict__ Wx,  const float* __restrict__ bx,
    const float* __restrict__ Wf,  const float* __restrict__ bf,
    const float* __restrict__ Wo,  const float* __restrict__ bo,
    const float* __restrict__ betap,
    const float* __restrict__ tv_ws, const float* __restrict__ dtv_ws,
    const float* __restrict__ consts,
    float* __restrict__ dsum, int* __restrict__ counter,
    float* __restrict__ out)
{
    const int tid  = threadIdx.x;
    const int gidx = tid & 127;
    const int rh   = tid >> 7;

    const float sig2     = consts[0];
    const float dlp      = consts[1];
    const float inv_s4   = consts[2];
    const float invZ     = consts[3];
    const float mu       = consts[4];
    const float inv_sig  = consts[5];
    const float sigma    = consts[6];
    const float inv_sig2 = frcp(sig2);

    float wx[16], wf[16];
    #pragma unroll
    for (int i=0;i<4;i++){
        float4 a4 = ((const float4*)(Wx + gidx*16))[i];
        wx[i*4+0]=a4.x; wx[i*4+1]=a4.y; wx[i*4+2]=a4.z; wx[i*4+3]=a4.w;
        float4 b4 = ((const float4*)(Wf + gidx*16))[i];
        wf[i*4+0]=b4.x; wf[i*4+1]=b4.y; wf[i*4+2]=b4.z; wf[i*4+3]=b4.w;
    }
    float4 t4;
    t4 = ((const float4*)bx)[gidx];     float bxA[4]={t4.x,t4.y,t4.z,t4.w};
    t4 = ((const float4*)bf)[gidx];     float bfA[4]={t4.x,t4.y,t4.z,t4.w};
    t4 = ((const float4*)Wo)[gidx];     float w3[4] ={t4.x,t4.y,t4.z,t4.w};
    t4 = ((const float4*)tv_ws)[gidx];  float tvA[4]={t4.x,t4.y,t4.z,t4.w};
    t4 = ((const float4*)dtv_ws)[gidx]; float dtvA[4]={t4.x,t4.y,t4.z,t4.w};
    const float bo0 = bo[gidx];
    const float bb  = betap[gidx];

    float dsdt_acc = 0.0f;
    f32x4 pde_park[4];
    const int row0 = blockIdx.x*8 + rh;

    #pragma unroll
    for (int it=0; it<4; it++){
        const int r = row0 + it*2;
        float4 zv = *((const float4*)(z + r*NIN + gidx*4));
        float zz[4]={zv.x,zv.y,zv.z,zv.w};

        // forward
        float x[4], xp[4], u1[4];
        #pragma unroll
        for (int i=0;i<4;i++){
            float a = bxA[i] + wx[i*4]*zz[0]+wx[i*4+1]*zz[1]+wx[i*4+2]*zz[2]+wx[i*4+3]*zz[3];
            x[i] = ftanh(a); xp[i] = 1.0f - x[i]*x[i];
            u1[i] = x[i] + tvA[i];
        }
        float h[4], hp[4];
        float a3 = bo0;
        #pragma unroll
        for (int i=0;i<4;i++){
            float a = bfA[i] + wf[i*4]*u1[0]+wf[i*4+1]*u1[1]+wf[i*4+2]*u1[2]+wf[i*4+3]*u1[3];
            h[i] = ftanh(a); hp[i] = 1.0f - h[i]*h[i];
            a3 += w3[i]*h[i];
        }
        float S = ftanh(a3), sp = 1.0f - S*S;

        // B[i,n] = sum_k Wf[i,k]*xp_k*Wx[k,n]
        float Bm[16];
        #pragma unroll
        for (int i=0;i<4;i++){
            #pragma unroll
            for (int n=0;n<4;n++){
                float s = 0.0f;
                #pragma unroll
                for (int k=0;k<4;k++) s += wf[i*4+k]*xp[k]*wx[k*4+n];
                Bm[i*4+n]=s;
            }
        }
        float w3hp[4], v[4];
        #pragma unroll
        for (int i=0;i<4;i++){ w3hp[i]=w3[i]*hp[i]; v[i]=sp*w3hp[i]; }
        float q[4]={0.f,0.f,0.f,0.f};
        #pragma unroll
        for (int i=0;i<4;i++){
            #pragma unroll
            for (int j=0;j<4;j++) q[j] += v[i]*wf[i*4+j];
        }
        dsdt_acc += q[0]*dtvA[0]+q[1]*dtvA[1]+q[2]*dtvA[2]+q[3]*dtvA[3];

        float c[4];
        #pragma unroll
        for (int n=0;n<4;n++){
            float s=0.0f;
            #pragma unroll
            for (int i=0;i<4;i++) s += w3hp[i]*Bm[i*4+n];
            c[n]=s;
        }
        const float alpha = -2.0f*S*sp;
        float bet[4], gam[4];
        #pragma unroll
        for (int i=0;i<4;i++){ bet[i] = -2.0f*h[i]*v[i]; gam[i] = -2.0f*x[i]*xp[i]*q[i]; }

        // rho / nlp / dpp
        float rho[4], nlp[4], dpp[4];
        #pragma unroll
        for (int j=0;j<4;j++){
            float zj = zz[j];
            float xs = zj > 10.0f ? zj+100.0f : zj;
            xs = xs < -10.0f ? xs-100.0f : xs;
            float xn = (xs-mu)*inv_sig;
            float dens = __expf(-0.5f*xn*xn)*INV_SQRT_2PI;
            dens = (xn > 10.0f || xn < -10.0f) ? 0.0f : dens;
            rho[j] = dens*invZ + 1e-10f;
            nlp[j] = -(zj-mu)*inv_sig2;
            float d = zj-mu;
            dpp[j] = (d*d - sigma*sigma)*inv_s4;
        }
        float u_val = S - bb*__logf(rho[0]*rho[1]*rho[2]*rho[3]);

        // contractions: H = alpha c c^T + sum_i bet_i B_i B_i^T + sum_k gam_k A_k A_k^T
        float rc=0.0f, scs=0.0f;
        #pragma unroll
        for (int j=0;j<4;j++){ rc += rho[j]*c[j]; scs += c[j]; }
        float rB[4], sB[4], rA[4], sA[4];
        #pragma unroll
        for (int i=0;i<4;i++){
            float r1=0.0f, s=0.0f, r2=0.0f, s2=0.0f;
            #pragma unroll
            for (int j=0;j<4;j++){
                r1 += rho[j]*Bm[i*4+j]; s  += Bm[i*4+j];
                r2 += rho[j]*wx[i*4+j]; s2 += wx[i*4+j];
            }
            rB[i]=r1; sB[i]=s; rA[i]=r2; sA[i]=s2;
        }

        float pde[4], uz[4], uzz[4];
        #pragma unroll
        for (int k=0;k<4;k++){
            float corr = alpha*rc*c[k];
            float hsum = alpha*scs*c[k];
            #pragma unroll
            for (int i=0;i<4;i++){
                corr += bet[i]*rB[i]*Bm[i*4+k];
                hsum += bet[i]*sB[i]*Bm[i*4+k];
                corr += gam[i]*rA[i]*wx[i*4+k];
                hsum += gam[i]*sA[i]*wx[i*4+k];
            }
            float uzk = sp*c[k] - bb*nlp[k];
            uz[k]  = uzk;
            uzz[k] = hsum - bb*dlp;
            pde[k] = bb*corr*frcp(rho[k]+1e-5f)
                   + 0.5f*uzk*uzk + 0.125f*bb*bb*(nlp[k]*nlp[k] - 2.0f*dpp[k]);
        }

        const int base = r*NIN + gidx*4;
        f32x4 uzv  = { uz[0],  uz[1],  uz[2],  uz[3]  };
        f32x4 uzzv = { uzz[0], uzz[1], uzz[2], uzz[3] };
        __builtin_nontemporal_store(uzv,  (f32x4*)(out + OFF1 + base));
        __builtin_nontemporal_store(u_val, out + OFF2 + r*NG + gidx);
        __builtin_nontemporal_store(uzzv, (f32x4*)(out + OFF3 + base));
        pde_park[it] = (f32x4){ pde[0], pde[1], pde[2], pde[3] };
    }

    // per-block dS/dt partial (LDS reduce), then device-scope accumulate
    __shared__ float sred[256];
    sred[tid] = dsdt_acc;
    __syncthreads();
    if (tid < 128) atomicAdd(&dsum[tid], sred[tid] + sred[tid+128]);

    // ---- manual grid barrier (all NBLK blocks co-resident by construction) ----
    __threadfence();   // make dsum adds visible device-wide
    if (tid == 0){
        __hip_atomic_fetch_add(counter, 1, __ATOMIC_RELEASE, __HIP_MEMORY_SCOPE_AGENT);
        while (__hip_atomic_load(counter, __ATOMIC_ACQUIRE, __HIP_MEMORY_SCOPE_AGENT) < NBLK)
            __builtin_amdgcn_s_sleep(2);
    }
    __syncthreads();

    const float dS = __hip_atomic_load(&dsum[gidx], __ATOMIC_RELAXED,
                                       __HIP_MEMORY_SCOPE_AGENT);
    #pragma unroll
    for (int it=0; it<4; it++){
        const int r = row0 + it*2;
        f32x4 p = pde_park[it];
        p.x += dS; p.y += dS; p.z += dS; p.w += dS;
        __builtin_nontemporal_store(p, (f32x4*)(out + r*NIN + gidx*4));
    }
}

extern "C" void kernel_launch(void* const* d_in, const int* in_sizes, int n_in,
                              void* d_out, int out_size, void* d_ws, size_t ws_size,
                              hipStream_t stream){
    (void)in_sizes; (void)n_in; (void)out_size; (void)ws_size;
    const float* z     = (const float*)d_in[0];
    const float* ts    = (const float*)d_in[1];
    const float* mu    = (const float*)d_in[2];
    const float* sigma = (const float*)d_in[3];
    const float* Wx    = (const float*)d_in[4];
    const float* bx    = (const float*)d_in[5];
    const float* Wt    = (const float*)d_in[6];
    const float* bt    = (const float*)d_in[7];
    const float* Wt2   = (const float*)d_in[8];
    const float* bt2   = (const float*)d_in[9];
    const float* Wf    = (const float*)d_in[10];
    const float* bf    = (const float*)d_in[11];
    const float* Wo    = (const float*)d_in[12];
    const float* bo    = (const float*)d_in[13];
    const float* beta  = (const float*)d_in[14];
    float* out = (float*)d_out;

    float* ws      = (float*)d_ws;
    float* tv_ws   = ws;            // 512
    float* dtv_ws  = ws + 512;      // 512
    float* consts  = ws + 1024;     // 8
    float* dsum    = ws + 1032;     // 128
    int*   counter = (int*)(ws + 1160);

    k_pre<<<1, 128, 0, stream>>>(ts, mu, sigma, Wt, bt, Wt2, bt2,
                                 tv_ws, dtv_ws, consts, dsum, counter);
    k_all<<<NBLK, 256, 0, stream>>>(z, Wx, bx, Wf, bf, Wo, bo, beta,
                                    tv_ws, dtv_ws, consts, dsum, counter, out);
}

// Round 8
// 176.494 us; speedup vs baseline: 3.3085x; 3.3085x over previous
//
#include <hip/hip_runtime.h>
#include <math.h>

#define NG 128
#define NIN 512
#define OFF1 4194304   // 8192*512
#define OFF2 8388608   // 2*8192*512
#define OFF3 9437184   // OFF2 + 8192*128

#define INV_SQRT_2PI 0.3989422804014327f
#define INV_SQRT2    0.7071067811865476f

typedef float f32x4 __attribute__((ext_vector_type(4)));

// fast tanh: 1 - 2/(e^{2x}+1). v_exp_f32 + v_rcp_f32, ~2ulp.
__device__ __forceinline__ float ftanh(float x){
    float e = __expf(2.0f*x);
    float r = __builtin_amdgcn_rcpf(e + 1.0f);
    return 1.0f - 2.0f*r;
}
__device__ __forceinline__ float frcp(float x){ return __builtin_amdgcn_rcpf(x); }

__device__ __forceinline__ float gelu_f(float x){
    return 0.5f*x*(1.0f + erff(x*INV_SQRT2));
}
__device__ __forceinline__ float gelu_df(float x){
    return 0.5f*(1.0f + erff(x*INV_SQRT2)) + x*INV_SQRT_2PI*__expf(-0.5f*x*x);
}

// Kernel 1: tv(t), dtv/dt, truncnorm consts; zeroes dsum (ws is re-poisoned
// to 0xAA before every timed call, so re-zero every call).
__global__ void k_pre(const float* __restrict__ ts,
                      const float* __restrict__ mup, const float* __restrict__ sigp,
                      const float* __restrict__ Wt,  const float* __restrict__ bt,
                      const float* __restrict__ Wt2, const float* __restrict__ bt2,
                      float* __restrict__ tv_ws, float* __restrict__ dtv_ws,
                      float* __restrict__ consts, float* __restrict__ dsum){
    int g = threadIdx.x;
    if (g < NG) dsum[g] = 0.0f;
    if (g == 0){
        float mu = mup[0], sigma = sigp[0];
        float sig2  = sigma*sigma + 1e-5f;
        float phi_b = 0.5f*(1.0f+erff((10.0f-mu)/sigma*INV_SQRT2));
        float phi_a = 0.5f*(1.0f+erff((-10.0f-mu)/sigma*INV_SQRT2));
        consts[0] = sig2;
        consts[1] = -1.0f/sig2;                                    // dlp
        consts[2] = 1.0f/(sigma*sigma*sigma*sigma + 1e-5f);        // inv_s4
        consts[3] = 1.0f/(phi_b-phi_a);                            // invZ
        consts[4] = mu;
        consts[5] = 1.0f/sigma;
        consts[6] = sigma;
    }
    if (g >= NG) return;
    float t  = ts[0];
    const float f1 = 0.01f;                     // freqs = [1, 0.01] exactly
    float s0, c0, s1, c1;
    __sincosf(t, &s0, &c0);
    __sincosf(t*f1, &s1, &c1);
    float temb[4]  = { s0, s1, c0, c1 };
    float dtemb[4] = { c0, f1*c1, -s0, -f1*s1 };
    float tg[4], dg[4];
    #pragma unroll
    for (int i=0;i<4;i++){
        float a = bt[g*4+i], d = 0.0f;
        #pragma unroll
        for (int j=0;j<4;j++){
            float w = Wt[g*16+i*4+j];
            a += w*temb[j]; d += w*dtemb[j];
        }
        tg[i] = gelu_f(a);
        dg[i] = gelu_df(a)*d;
    }
    #pragma unroll
    for (int j=0;j<4;j++){
        float a = bt2[g*4+j], d = 0.0f;
        #pragma unroll
        for (int i=0;i<4;i++){
            float w = Wt2[g*16+j*4+i];
            a += w*tg[i]; d += w*dg[i];
        }
        tv_ws[g*4+j]  = a;
        dtv_ws[g*4+j] = d;
    }
}

// Main kernel: 2048 blocks x 256 threads; thread = (g = tid&127) x 2 rows,
// forward pass INTERLEAVED across the 2 rows for ILP on the serial
// exp->rcp tanh chains (the measured latency bottleneck). dS/dt partial is
// reduced and atomically accumulated MID-kernel so the atomic tail hides
// under the Hessian epilogue. pde is written minus the dSdt broadcast
// (k_fix adds it); pde normal store (re-read), uz/u/uzz nontemporal.
__global__ __launch_bounds__(256, 3) void k_main(const float* __restrict__ z,
    const float* __restrict__ Wx, const float* __restrict__ bx,
    const float* __restrict__ Wf, const float* __restrict__ bf,
    const float* __restrict__ Wo, const float* __restrict__ bo,
    const float* __restrict__ betap, const float* __restrict__ tv_ws,
    const float* __restrict__ dtv_ws, const float* __restrict__ consts,
    float* __restrict__ dsum, float* __restrict__ out){
    const int tid  = threadIdx.x;
    const int gidx = tid & 127;
    const int row0 = blockIdx.x*4 + (tid>>7)*2;   // rows row0, row0+1

    const float sig2    = consts[0];
    const float dlp     = consts[1];
    const float inv_s4  = consts[2];
    const float invZ    = consts[3];
    const float mu      = consts[4];
    const float inv_sig = consts[5];
    const float sigma   = consts[6];
    const float inv_sig2 = frcp(sig2);

    float wx[16], wf[16];
    #pragma unroll
    for (int i=0;i<4;i++){
        float4 a4 = ((const float4*)(Wx + gidx*16))[i];
        wx[i*4+0]=a4.x; wx[i*4+1]=a4.y; wx[i*4+2]=a4.z; wx[i*4+3]=a4.w;
        float4 b4 = ((const float4*)(Wf + gidx*16))[i];
        wf[i*4+0]=b4.x; wf[i*4+1]=b4.y; wf[i*4+2]=b4.z; wf[i*4+3]=b4.w;
    }
    float4 t4;
    t4 = ((const float4*)bx)[gidx];     float bxA[4]={t4.x,t4.y,t4.z,t4.w};
    t4 = ((const float4*)bf)[gidx];     float bfA[4]={t4.x,t4.y,t4.z,t4.w};
    t4 = ((const float4*)Wo)[gidx];     float w3[4] ={t4.x,t4.y,t4.z,t4.w};
    t4 = ((const float4*)tv_ws)[gidx];  float tvA[4]={t4.x,t4.y,t4.z,t4.w};
    t4 = ((const float4*)dtv_ws)[gidx]; float dtvA[4]={t4.x,t4.y,t4.z,t4.w};
    const float bo0 = bo[gidx];
    const float bb  = betap[gidx];

    // ---- interleaved forward for both rows (2x ILP on tanh chains) ----
    float zz[2][4], x_[2][4], xp[2][4], h_[2][4], hp[2][4], S[2], sp[2], q[2][4];
    #pragma unroll
    for (int r=0;r<2;r++){
        float4 zv = *((const float4*)(z + (row0+r)*NIN + gidx*4));
        zz[r][0]=zv.x; zz[r][1]=zv.y; zz[r][2]=zv.z; zz[r][3]=zv.w;
    }
    float u1[2][4];
    #pragma unroll
    for (int r=0;r<2;r++){
        #pragma unroll
        for (int i=0;i<4;i++){
            float a = bxA[i] + wx[i*4]*zz[r][0]+wx[i*4+1]*zz[r][1]
                             + wx[i*4+2]*zz[r][2]+wx[i*4+3]*zz[r][3];
            x_[r][i] = ftanh(a);
        }
    }
    #pragma unroll
    for (int r=0;r<2;r++){
        #pragma unroll
        for (int i=0;i<4;i++){
            xp[r][i] = 1.0f - x_[r][i]*x_[r][i];
            u1[r][i] = x_[r][i] + tvA[i];
        }
    }
    float a3[2] = { bo0, bo0 };
    #pragma unroll
    for (int r=0;r<2;r++){
        #pragma unroll
        for (int i=0;i<4;i++){
            float a = bfA[i] + wf[i*4]*u1[r][0]+wf[i*4+1]*u1[r][1]
                             + wf[i*4+2]*u1[r][2]+wf[i*4+3]*u1[r][3];
            h_[r][i] = ftanh(a);
        }
    }
    #pragma unroll
    for (int r=0;r<2;r++){
        #pragma unroll
        for (int i=0;i<4;i++){
            hp[r][i] = 1.0f - h_[r][i]*h_[r][i];
            a3[r] += w3[i]*h_[r][i];
        }
    }
    #pragma unroll
    for (int r=0;r<2;r++){ S[r] = ftanh(a3[r]); sp[r] = 1.0f - S[r]*S[r]; }
    #pragma unroll
    for (int r=0;r<2;r++){
        q[r][0]=q[r][1]=q[r][2]=q[r][3]=0.0f;
        #pragma unroll
        for (int i=0;i<4;i++){
            float vi = sp[r]*w3[i]*hp[r][i];
            #pragma unroll
            for (int j=0;j<4;j++) q[r][j] += vi*wf[i*4+j];
        }
    }

    // ---- dS/dt partial: LDS-reduce + device atomic, EARLY (tail hides) ----
    {
        float acc = (q[0][0]+q[1][0])*dtvA[0] + (q[0][1]+q[1][1])*dtvA[1]
                  + (q[0][2]+q[1][2])*dtvA[2] + (q[0][3]+q[1][3])*dtvA[3];
        __shared__ float sred[256];
        sred[tid] = acc;
        __syncthreads();
        if (tid < 128) atomicAdd(&dsum[tid], sred[tid] + sred[tid+128]);
    }

    // ---- epilogue per row (sequential: caps VGPR; plenty of intra-row ILP) ----
    #pragma unroll
    for (int r=0;r<2;r++){
        float Bm[16];
        #pragma unroll
        for (int i=0;i<4;i++){
            #pragma unroll
            for (int n=0;n<4;n++){
                float s = 0.0f;
                #pragma unroll
                for (int k=0;k<4;k++) s += wf[i*4+k]*xp[r][k]*wx[k*4+n];
                Bm[i*4+n]=s;
            }
        }
        float w3hp[4], v[4];
        #pragma unroll
        for (int i=0;i<4;i++){ w3hp[i]=w3[i]*hp[r][i]; v[i]=sp[r]*w3hp[i]; }
        float c[4];
        #pragma unroll
        for (int n=0;n<4;n++){
            float s=0.0f;
            #pragma unroll
            for (int i=0;i<4;i++) s += w3hp[i]*Bm[i*4+n];
            c[n]=s;
        }
        const float alpha = -2.0f*S[r]*sp[r];
        float bet[4], gam[4];
        #pragma unroll
        for (int i=0;i<4;i++){
            bet[i] = -2.0f*h_[r][i]*v[i];
            gam[i] = -2.0f*x_[r][i]*xp[r][i]*q[r][i];
        }

        float rho[4], nlp[4], dpp[4];
        #pragma unroll
        for (int j=0;j<4;j++){
            float zj = zz[r][j];
            float xs = zj > 10.0f ? zj+100.0f : zj;
            xs = xs < -10.0f ? xs-100.0f : xs;
            float xn = (xs-mu)*inv_sig;
            float dens = __expf(-0.5f*xn*xn)*INV_SQRT_2PI;
            dens = (xn > 10.0f || xn < -10.0f) ? 0.0f : dens;
            rho[j] = dens*invZ + 1e-10f;
            nlp[j] = -(zj-mu)*inv_sig2;
            float d = zj-mu;
            dpp[j] = (d*d - sigma*sigma)*inv_s4;
        }
        float u_val = S[r] - bb*__logf(rho[0]*rho[1]*rho[2]*rho[3]);

        float rc=0.0f, scs=0.0f;
        #pragma unroll
        for (int j=0;j<4;j++){ rc += rho[j]*c[j]; scs += c[j]; }
        float rB[4], sB[4], rA[4], sA[4];
        #pragma unroll
        for (int i=0;i<4;i++){
            float r1=0.0f, s=0.0f, r2=0.0f, s2=0.0f;
            #pragma unroll
            for (int j=0;j<4;j++){
                r1 += rho[j]*Bm[i*4+j]; s  += Bm[i*4+j];
                r2 += rho[j]*wx[i*4+j]; s2 += wx[i*4+j];
            }
            rB[i]=r1; sB[i]=s; rA[i]=r2; sA[i]=s2;
        }

        float pde[4], uz[4], uzz[4];
        #pragma unroll
        for (int k=0;k<4;k++){
            float corr = alpha*rc*c[k];
            float hsum = alpha*scs*c[k];
            #pragma unroll
            for (int i=0;i<4;i++){
                corr += bet[i]*rB[i]*Bm[i*4+k];
                hsum += bet[i]*sB[i]*Bm[i*4+k];
                corr += gam[i]*rA[i]*wx[i*4+k];
                hsum += gam[i]*sA[i]*wx[i*4+k];
            }
            float uzk = sp[r]*c[k] - bb*nlp[k];
            uz[k]  = uzk;
            uzz[k] = hsum - bb*dlp;
            pde[k] = bb*corr*frcp(rho[k]+1e-5f)
                   + 0.5f*uzk*uzk + 0.125f*bb*bb*(nlp[k]*nlp[k] - 2.0f*dpp[k]);
        }

        const int base = (row0+r)*NIN + gidx*4;
        *((float4*)(out + base)) = make_float4(pde[0],pde[1],pde[2],pde[3]);
        f32x4 uzv  = { uz[0],  uz[1],  uz[2],  uz[3]  };
        f32x4 uzzv = { uzz[0], uzz[1], uzz[2], uzz[3] };
        __builtin_nontemporal_store(uzv,  (f32x4*)(out + OFF1 + base));
        __builtin_nontemporal_store(u_val, out + OFF2 + (row0+r)*NG + gidx);
        __builtin_nontemporal_store(uzzv, (f32x4*)(out + OFF3 + base));
    }
}

// pde += dsum[g]. 4096 blocks x 256 threads, one float4 per thread.
__global__ __launch_bounds__(256) void k_fix(const float* __restrict__ dsum,
                                             float* __restrict__ out){
    const int idx = blockIdx.x*256 + threadIdx.x;   // float4 index; g = idx&127
    const float ds = dsum[threadIdx.x & 127];
    float4* p = ((float4*)out) + idx;
    float4 v = *p;
    v.x += ds; v.y += ds; v.z += ds; v.w += ds;
    *p = v;
}

extern "C" void kernel_launch(void* const* d_in, const int* in_sizes, int n_in,
                              void* d_out, int out_size, void* d_ws, size_t ws_size,
                              hipStream_t stream){
    (void)in_sizes; (void)n_in; (void)out_size; (void)ws_size;
    const float* z     = (const float*)d_in[0];
    const float* ts    = (const float*)d_in[1];
    const float* mu    = (const float*)d_in[2];
    const float* sigma = (const float*)d_in[3];
    const float* Wx    = (const float*)d_in[4];
    const float* bx    = (const float*)d_in[5];
    const float* Wt    = (const float*)d_in[6];
    const float* bt    = (const float*)d_in[7];
    const float* Wt2   = (const float*)d_in[8];
    const float* bt2   = (const float*)d_in[9];
    const float* Wf    = (const float*)d_in[10];
    const float* bf    = (const float*)d_in[11];
    const float* Wo    = (const float*)d_in[12];
    const float* bo    = (const float*)d_in[13];
    const float* beta  = (const float*)d_in[14];
    float* out = (float*)d_out;

    float* ws      = (float*)d_ws;
    float* tv_ws   = ws;            // 512
    float* dtv_ws  = ws + 512;      // 512
    float* consts  = ws + 1024;     // 8
    float* dsum    = ws + 1032;     // 128

    k_pre <<<1,   128, 0, stream>>>(ts, mu, sigma, Wt, bt, Wt2, bt2,
                                    tv_ws, dtv_ws, consts, dsum);
    k_main<<<2048,256, 0, stream>>>(z, Wx, bx, Wf, bf, Wo, bo, beta, tv_ws,
                                    dtv_ws, consts, dsum, out);
    k_fix <<<4096,256, 0, stream>>>(dsum, out);
}

// Round 9
// 126.122 us; speedup vs baseline: 4.6299x; 1.3994x over previous
//
#include <hip/hip_runtime.h>
#include <math.h>

#define NG 128
#define NIN 512
#define OFF1 4194304   // 8192*512
#define OFF2 8388608   // 2*8192*512
#define OFF3 9437184   // OFF2 + 8192*128

#define INV_SQRT_2PI 0.3989422804014327f
#define INV_SQRT2    0.7071067811865476f

typedef float f32x4 __attribute__((ext_vector_type(4)));

// fast tanh: 1 - 2/(e^{2x}+1). v_exp_f32 + v_rcp_f32, ~2ulp.
__device__ __forceinline__ float ftanh(float x){
    float e = __expf(2.0f*x);
    float r = __builtin_amdgcn_rcpf(e + 1.0f);
    return 1.0f - 2.0f*r;
}
__device__ __forceinline__ float frcp(float x){ return __builtin_amdgcn_rcpf(x); }

__device__ __forceinline__ float gelu_f(float x){
    return 0.5f*x*(1.0f + erff(x*INV_SQRT2));
}
__device__ __forceinline__ float gelu_df(float x){
    return 0.5f*(1.0f + erff(x*INV_SQRT2)) + x*INV_SQRT_2PI*__expf(-0.5f*x*x);
}

// Kernel 1: tv(t), dtv/dt, truncnorm consts (expensive OCML once).
__global__ void k_pre(const float* __restrict__ ts,
                      const float* __restrict__ mup, const float* __restrict__ sigp,
                      const float* __restrict__ Wt,  const float* __restrict__ bt,
                      const float* __restrict__ Wt2, const float* __restrict__ bt2,
                      float* __restrict__ tv_ws, float* __restrict__ dtv_ws,
                      float* __restrict__ consts){
    int g = threadIdx.x;
    if (g == 0){
        float mu = mup[0], sigma = sigp[0];
        float sig2  = sigma*sigma + 1e-5f;
        float phi_b = 0.5f*(1.0f+erff((10.0f-mu)/sigma*INV_SQRT2));
        float phi_a = 0.5f*(1.0f+erff((-10.0f-mu)/sigma*INV_SQRT2));
        consts[0] = sig2;
        consts[1] = -1.0f/sig2;                                    // dlp
        consts[2] = 1.0f/(sigma*sigma*sigma*sigma + 1e-5f);        // inv_s4
        consts[3] = 1.0f/(phi_b-phi_a);                            // invZ
        consts[4] = mu;
        consts[5] = 1.0f/sigma;
        consts[6] = sigma;
    }
    if (g >= NG) return;
    float t  = ts[0];
    const float f1 = 0.01f;                     // freqs = [1, 0.01] exactly
    float s0, c0, s1, c1;
    __sincosf(t, &s0, &c0);
    __sincosf(t*f1, &s1, &c1);
    float temb[4]  = { s0, s1, c0, c1 };
    float dtemb[4] = { c0, f1*c1, -s0, -f1*s1 };
    float tg[4], dg[4];
    #pragma unroll
    for (int i=0;i<4;i++){
        float a = bt[g*4+i], d = 0.0f;
        #pragma unroll
        for (int j=0;j<4;j++){
            float w = Wt[g*16+i*4+j];
            a += w*temb[j]; d += w*dtemb[j];
        }
        tg[i] = gelu_f(a);
        dg[i] = gelu_df(a)*d;
    }
    #pragma unroll
    for (int j=0;j<4;j++){
        float a = bt2[g*4+j], d = 0.0f;
        #pragma unroll
        for (int i=0;i<4;i++){
            float w = Wt2[g*16+j*4+i];
            a += w*tg[i]; d += w*dg[i];
        }
        tv_ws[g*4+j]  = a;
        dtv_ws[g*4+j] = d;
    }
}

// Kernel 2: forward-only dS/dt partials, 4 rows/thread with the forward
// INTERLEAVED across rows (16 independent tanh chains in flight — attacks
// the measured latency-bound stall). 1024 blocks x 256; deterministic
// per-block partial at the end, NO atomics (R7/R8 lesson).
__global__ __launch_bounds__(256) void k_dsdt(const float* __restrict__ z,
    const float* __restrict__ Wx, const float* __restrict__ bx,
    const float* __restrict__ Wf, const float* __restrict__ bf,
    const float* __restrict__ Wo, const float* __restrict__ bo,
    const float* __restrict__ tv_ws, const float* __restrict__ dtv_ws,
    float* __restrict__ partial){
    const int tid  = threadIdx.x;
    const int gidx = tid & 127;
    const int lb   = tid >> 7;
    float wx[16], wf[16];
    #pragma unroll
    for (int i=0;i<4;i++){
        float4 a4 = ((const float4*)(Wx + gidx*16))[i];
        wx[i*4+0]=a4.x; wx[i*4+1]=a4.y; wx[i*4+2]=a4.z; wx[i*4+3]=a4.w;
        float4 b4 = ((const float4*)(Wf + gidx*16))[i];
        wf[i*4+0]=b4.x; wf[i*4+1]=b4.y; wf[i*4+2]=b4.z; wf[i*4+3]=b4.w;
    }
    float4 t4;
    t4 = ((const float4*)bx)[gidx];     float bxA[4]={t4.x,t4.y,t4.z,t4.w};
    t4 = ((const float4*)bf)[gidx];     float bfA[4]={t4.x,t4.y,t4.z,t4.w};
    t4 = ((const float4*)Wo)[gidx];     float w3[4] ={t4.x,t4.y,t4.z,t4.w};
    t4 = ((const float4*)tv_ws)[gidx];  float tvA[4]={t4.x,t4.y,t4.z,t4.w};
    t4 = ((const float4*)dtv_ws)[gidx]; float dtvA[4]={t4.x,t4.y,t4.z,t4.w};
    const float bo0 = bo[gidx];

    const int r0 = blockIdx.x*8 + lb*4;

    // interleaved loads
    float zz[4][4];
    #pragma unroll
    for (int r=0;r<4;r++){
        float4 zv = *((const float4*)(z + (r0+r)*NIN + gidx*4));
        zz[r][0]=zv.x; zz[r][1]=zv.y; zz[r][2]=zv.z; zz[r][3]=zv.w;
    }
    // stage 1: 16 independent tanh
    float u1[4][4];
    #pragma unroll
    for (int r=0;r<4;r++){
        #pragma unroll
        for (int i=0;i<4;i++){
            float a = bxA[i] + wx[i*4]*zz[r][0]+wx[i*4+1]*zz[r][1]
                             + wx[i*4+2]*zz[r][2]+wx[i*4+3]*zz[r][3];
            u1[r][i] = ftanh(a) + tvA[i];
        }
    }
    // stage 2: 16 independent tanh
    float hp[4][4], a3[4];
    #pragma unroll
    for (int r=0;r<4;r++) a3[r] = bo0;
    #pragma unroll
    for (int r=0;r<4;r++){
        #pragma unroll
        for (int i=0;i<4;i++){
            float a = bfA[i] + wf[i*4]*u1[r][0]+wf[i*4+1]*u1[r][1]
                             + wf[i*4+2]*u1[r][2]+wf[i*4+3]*u1[r][3];
            float h = ftanh(a);
            hp[r][i] = 1.0f - h*h;
            a3[r] += w3[i]*h;
        }
    }
    // stage 3: 4 independent tanh + q·dtv
    float acc = 0.0f;
    #pragma unroll
    for (int r=0;r<4;r++){
        float S = ftanh(a3[r]), sp = 1.0f - S*S;
        float q0=0,q1=0,q2=0,q3=0;
        #pragma unroll
        for (int i=0;i<4;i++){
            float vi = sp*w3[i]*hp[r][i];
            q0 += vi*wf[i*4+0]; q1 += vi*wf[i*4+1];
            q2 += vi*wf[i*4+2]; q3 += vi*wf[i*4+3];
        }
        acc += q0*dtvA[0]+q1*dtvA[1]+q2*dtvA[2]+q3*dtvA[3];
    }

    __shared__ float sred[256];
    sred[tid] = acc;
    __syncthreads();
    if (tid < 128) partial[blockIdx.x*128 + tid] = sred[tid] + sred[tid+128];
}

// Kernel 3: reduce 1024 partials per group -> dsum[g]. 128 blocks x 256.
__global__ __launch_bounds__(256) void k_red(const float* __restrict__ partial,
                                             float* __restrict__ dsum){
    int g = blockIdx.x;
    int tid = threadIdx.x;
    float a = 0.0f;
    for (int i=tid;i<1024;i+=256) a += partial[i*128+g];
    __shared__ float s[256];
    s[tid] = a;
    __syncthreads();
    if (tid < 64){
        a = s[tid] + s[tid+64] + s[tid+128] + s[tid+192];
        #pragma unroll
        for (int o=32;o>0;o>>=1) a += __shfl_down(a, o);
        if (tid==0) dsum[g] = a;
    }
}

// Kernel 4: full computation. 2048 blocks x 256; thread = (g) x 2 rows.
// Forward interleaved across the 2 rows (ILP on tanh chains); epilogue
// sequential per row (caps VGPR). No barrier, no atomic, dsum inline.
__global__ __launch_bounds__(256) void k_main(const float* __restrict__ z,
    const float* __restrict__ Wx, const float* __restrict__ bx,
    const float* __restrict__ Wf, const float* __restrict__ bf,
    const float* __restrict__ Wo, const float* __restrict__ bo,
    const float* __restrict__ betap, const float* __restrict__ tv_ws,
    const float* __restrict__ consts,
    const float* __restrict__ dsum, float* __restrict__ out){
    const int tid  = threadIdx.x;
    const int gidx = tid & 127;
    const int row0 = blockIdx.x*4 + (tid>>7)*2;   // rows row0, row0+1

    const float sig2    = consts[0];
    const float dlp     = consts[1];
    const float inv_s4  = consts[2];
    const float invZ    = consts[3];
    const float mu      = consts[4];
    const float inv_sig = consts[5];
    const float sigma   = consts[6];
    const float inv_sig2 = frcp(sig2);

    float wx[16], wf[16];
    #pragma unroll
    for (int i=0;i<4;i++){
        float4 a4 = ((const float4*)(Wx + gidx*16))[i];
        wx[i*4+0]=a4.x; wx[i*4+1]=a4.y; wx[i*4+2]=a4.z; wx[i*4+3]=a4.w;
        float4 b4 = ((const float4*)(Wf + gidx*16))[i];
        wf[i*4+0]=b4.x; wf[i*4+1]=b4.y; wf[i*4+2]=b4.z; wf[i*4+3]=b4.w;
    }
    float4 t4;
    t4 = ((const float4*)bx)[gidx];    float bxA[4]={t4.x,t4.y,t4.z,t4.w};
    t4 = ((const float4*)bf)[gidx];    float bfA[4]={t4.x,t4.y,t4.z,t4.w};
    t4 = ((const float4*)Wo)[gidx];    float w3[4] ={t4.x,t4.y,t4.z,t4.w};
    t4 = ((const float4*)tv_ws)[gidx]; float tvA[4]={t4.x,t4.y,t4.z,t4.w};
    const float bo0    = bo[gidx];
    const float bb     = betap[gidx];
    const float dS_sum = dsum[gidx];

    // ---- interleaved forward for 2 rows ----
    float zz[2][4], x_[2][4], xp[2][4], h_[2][4], hp[2][4], S[2], sp[2], q[2][4];
    #pragma unroll
    for (int r=0;r<2;r++){
        float4 zv = *((const float4*)(z + (row0+r)*NIN + gidx*4));
        zz[r][0]=zv.x; zz[r][1]=zv.y; zz[r][2]=zv.z; zz[r][3]=zv.w;
    }
    float u1[2][4];
    #pragma unroll
    for (int r=0;r<2;r++){
        #pragma unroll
        for (int i=0;i<4;i++){
            float a = bxA[i] + wx[i*4]*zz[r][0]+wx[i*4+1]*zz[r][1]
                             + wx[i*4+2]*zz[r][2]+wx[i*4+3]*zz[r][3];
            x_[r][i] = ftanh(a);
        }
    }
    #pragma unroll
    for (int r=0;r<2;r++){
        #pragma unroll
        for (int i=0;i<4;i++){
            xp[r][i] = 1.0f - x_[r][i]*x_[r][i];
            u1[r][i] = x_[r][i] + tvA[i];
        }
    }
    float a3[2] = { bo0, bo0 };
    #pragma unroll
    for (int r=0;r<2;r++){
        #pragma unroll
        for (int i=0;i<4;i++){
            float a = bfA[i] + wf[i*4]*u1[r][0]+wf[i*4+1]*u1[r][1]
                             + wf[i*4+2]*u1[r][2]+wf[i*4+3]*u1[r][3];
            h_[r][i] = ftanh(a);
        }
    }
    #pragma unroll
    for (int r=0;r<2;r++){
        #pragma unroll
        for (int i=0;i<4;i++){
            hp[r][i] = 1.0f - h_[r][i]*h_[r][i];
            a3[r] += w3[i]*h_[r][i];
        }
    }
    #pragma unroll
    for (int r=0;r<2;r++){ S[r] = ftanh(a3[r]); sp[r] = 1.0f - S[r]*S[r]; }
    #pragma unroll
    for (int r=0;r<2;r++){
        q[r][0]=q[r][1]=q[r][2]=q[r][3]=0.0f;
        #pragma unroll
        for (int i=0;i<4;i++){
            float vi = sp[r]*w3[i]*hp[r][i];
            #pragma unroll
            for (int j=0;j<4;j++) q[r][j] += vi*wf[i*4+j];
        }
    }

    // ---- epilogue per row ----
    #pragma unroll
    for (int r=0;r<2;r++){
        float Bm[16];
        #pragma unroll
        for (int i=0;i<4;i++){
            #pragma unroll
            for (int n=0;n<4;n++){
                float s = 0.0f;
                #pragma unroll
                for (int k=0;k<4;k++) s += wf[i*4+k]*xp[r][k]*wx[k*4+n];
                Bm[i*4+n]=s;
            }
        }
        float w3hp[4], v[4];
        #pragma unroll
        for (int i=0;i<4;i++){ w3hp[i]=w3[i]*hp[r][i]; v[i]=sp[r]*w3hp[i]; }
        float c[4];
        #pragma unroll
        for (int n=0;n<4;n++){
            float s=0.0f;
            #pragma unroll
            for (int i=0;i<4;i++) s += w3hp[i]*Bm[i*4+n];
            c[n]=s;
        }
        const float alpha = -2.0f*S[r]*sp[r];
        float bet[4], gam[4];
        #pragma unroll
        for (int i=0;i<4;i++){
            bet[i] = -2.0f*h_[r][i]*v[i];
            gam[i] = -2.0f*x_[r][i]*xp[r][i]*q[r][i];
        }

        float rho[4], nlp[4], dpp[4];
        #pragma unroll
        for (int j=0;j<4;j++){
            float zj = zz[r][j];
            float xs = zj > 10.0f ? zj+100.0f : zj;
            xs = xs < -10.0f ? xs-100.0f : xs;
            float xn = (xs-mu)*inv_sig;
            float dens = __expf(-0.5f*xn*xn)*INV_SQRT_2PI;
            dens = (xn > 10.0f || xn < -10.0f) ? 0.0f : dens;
            rho[j] = dens*invZ + 1e-10f;
            nlp[j] = -(zj-mu)*inv_sig2;
            float d = zj-mu;
            dpp[j] = (d*d - sigma*sigma)*inv_s4;
        }
        float u_val = S[r] - bb*__logf(rho[0]*rho[1]*rho[2]*rho[3]);

        float rc=0.0f, scs=0.0f;
        #pragma unroll
        for (int j=0;j<4;j++){ rc += rho[j]*c[j]; scs += c[j]; }
        float rB[4], sB[4], rA[4], sA[4];
        #pragma unroll
        for (int i=0;i<4;i++){
            float r1=0.0f, s=0.0f, r2=0.0f, s2=0.0f;
            #pragma unroll
            for (int j=0;j<4;j++){
                r1 += rho[j]*Bm[i*4+j]; s  += Bm[i*4+j];
                r2 += rho[j]*wx[i*4+j]; s2 += wx[i*4+j];
            }
            rB[i]=r1; sB[i]=s; rA[i]=r2; sA[i]=s2;
        }

        float pde[4], uz[4], uzz[4];
        #pragma unroll
        for (int k=0;k<4;k++){
            float corr = alpha*rc*c[k];
            float hsum = alpha*scs*c[k];
            #pragma unroll
            for (int i=0;i<4;i++){
                corr += bet[i]*rB[i]*Bm[i*4+k];
                hsum += bet[i]*sB[i]*Bm[i*4+k];
                corr += gam[i]*rA[i]*wx[i*4+k];
                hsum += gam[i]*sA[i]*wx[i*4+k];
            }
            float uzk = sp[r]*c[k] - bb*nlp[k];
            uz[k]  = uzk;
            uzz[k] = hsum - bb*dlp;
            pde[k] = dS_sum + bb*corr*frcp(rho[k]+1e-5f)
                   + 0.5f*uzk*uzk + 0.125f*bb*bb*(nlp[k]*nlp[k] - 2.0f*dpp[k]);
        }

        const int base = (row0+r)*NIN + gidx*4;
        f32x4 pdev = { pde[0], pde[1], pde[2], pde[3] };
        f32x4 uzv  = { uz[0],  uz[1],  uz[2],  uz[3]  };
        f32x4 uzzv = { uzz[0], uzz[1], uzz[2], uzz[3] };
        __builtin_nontemporal_store(pdev, (f32x4*)(out + base));
        __builtin_nontemporal_store(uzv,  (f32x4*)(out + OFF1 + base));
        __builtin_nontemporal_store(u_val, out + OFF2 + (row0+r)*NG + gidx);
        __builtin_nontemporal_store(uzzv, (f32x4*)(out + OFF3 + base));
    }
}

extern "C" void kernel_launch(void* const* d_in, const int* in_sizes, int n_in,
                              void* d_out, int out_size, void* d_ws, size_t ws_size,
                              hipStream_t stream){
    (void)in_sizes; (void)n_in; (void)out_size; (void)ws_size;
    const float* z     = (const float*)d_in[0];
    const float* ts    = (const float*)d_in[1];
    const float* mu    = (const float*)d_in[2];
    const float* sigma = (const float*)d_in[3];
    const float* Wx    = (const float*)d_in[4];
    const float* bx    = (const float*)d_in[5];
    const float* Wt    = (const float*)d_in[6];
    const float* bt    = (const float*)d_in[7];
    const float* Wt2   = (const float*)d_in[8];
    const float* bt2   = (const float*)d_in[9];
    const float* Wf    = (const float*)d_in[10];
    const float* bf    = (const float*)d_in[11];
    const float* Wo    = (const float*)d_in[12];
    const float* bo    = (const float*)d_in[13];
    const float* beta  = (const float*)d_in[14];
    float* out = (float*)d_out;

    float* ws      = (float*)d_ws;
    float* tv_ws   = ws;            // 512
    float* dtv_ws  = ws + 512;      // 512
    float* consts  = ws + 1024;     // 8
    float* dsum    = ws + 1032;     // 128
    float* partial = ws + 1160;     // 1024*128 = 131072

    k_pre <<<1,   128, 0, stream>>>(ts, mu, sigma, Wt, bt, Wt2, bt2,
                                    tv_ws, dtv_ws, consts);
    k_dsdt<<<1024,256, 0, stream>>>(z, Wx, bx, Wf, bf, Wo, bo, tv_ws, dtv_ws, partial);
    k_red <<<128, 256, 0, stream>>>(partial, dsum);
    k_main<<<2048,256, 0, stream>>>(z, Wx, bx, Wf, bf, Wo, bo, beta, tv_ws,
                                    consts, dsum, out);
}